// Round 5
// baseline (39.746 us; speedup 1.0000x reference)
//
#include <hip/hip_runtime.h>
#include <cstdint>

typedef unsigned long long u64;
typedef unsigned int u32;

#define BB 64
#define DD 128
#define OO 512
#define II 512
#define OT 32              // o-tile per compute block (32 -> 2048 blocks)
#define XROWS (BB * DD)    // 8192 packed x rows

// ---------------------------------------------------------------------------
// Input-format detection (uniform -> scalar loads, same result every wave).
// mode 0: raw bytes {0,1} | mode 1: int32 {0,1} | mode 2: float32 {0.f,1.f}
// ---------------------------------------------------------------------------
__device__ __forceinline__ int detect_mode(const u32* __restrict__ w) {
    bool all01 = true, allf = true;
#pragma unroll
    for (int i = 0; i < 32; ++i) {
        u32 v = w[i];
        all01 = all01 && (v <= 1u);
        allf  = allf  && (v == 0u || v == 0x3F800000u);
    }
    return all01 ? 1 : (allf ? 2 : 0);
}

// ---------------------------------------------------------------------------
// Wave-cooperatively pack one 512-element binary row into 8 u64 words.
// Loads are lane-adjacent and fully coalesced. 8 ballots produce the packed
// words; the bit mapping is a fixed bijection identical for x and w rows, so
// popcount(xor) counts mismatches exactly. Lane j (j<8) returns word j.
// ---------------------------------------------------------------------------
__device__ __forceinline__ u64 pack_row(const void* __restrict__ src,
                                        size_t elem0, int mode, int lane) {
    u64 my = 0;
    if (mode == 0) {
        u64 v = *(const u64*)((const uint8_t*)src + elem0 + (size_t)lane * 8);
#pragma unroll
        for (int j = 0; j < 8; ++j) {
            u64 bj = __ballot(((u32)(v >> (8 * j))) & 1u);
            if (lane == j) my = bj;
        }
    } else {
        const u32 sh = (mode == 1) ? 0u : 23u;   // int32: bit0; float: bit23
        const uint4* p = (const uint4*)((const u32*)src + elem0);
        uint4 v0 = p[lane];        // elems [4L, 4L+4)
        uint4 v1 = p[64 + lane];   // elems [256+4L, 256+4L+4)
        u32 b0 = (v0.x >> sh) & 1u, b1 = (v0.y >> sh) & 1u;
        u32 b2 = (v0.z >> sh) & 1u, b3 = (v0.w >> sh) & 1u;
        u32 b4 = (v1.x >> sh) & 1u, b5 = (v1.y >> sh) & 1u;
        u32 b6 = (v1.z >> sh) & 1u, b7 = (v1.w >> sh) & 1u;
        u64 w0 = __ballot(b0), w1 = __ballot(b1), w2 = __ballot(b2), w3 = __ballot(b3);
        u64 w4 = __ballot(b4), w5 = __ballot(b5), w6 = __ballot(b6), w7 = __ballot(b7);
        if (lane == 0) my = w0;  if (lane == 1) my = w1;
        if (lane == 2) my = w2;  if (lane == 3) my = w3;
        if (lane == 4) my = w4;  if (lane == 5) my = w5;
        if (lane == 6) my = w6;  if (lane == 7) my = w7;
    }
    return my;
}

// ---------------------------------------------------------------------------
// Kernel 1: pack x (B*D rows) into d_ws. 512 KB output, L2-resident.
// ---------------------------------------------------------------------------
__global__ __launch_bounds__(256)
void pack_x_kernel(const void* __restrict__ x, const void* __restrict__ w,
                   u64* __restrict__ packed) {
    const int gtid = blockIdx.x * 256 + threadIdx.x;
    const int row  = gtid >> 6;          // 0..XROWS-1 (grid sized exactly)
    const int lane = threadIdx.x & 63;
    const int mode = detect_mode((const u32*)w);
    u64 my = pack_row(x, (size_t)row * II, mode, lane);
    if (lane < 8) packed[(size_t)row * 8 + lane] = my;
}

// ---------------------------------------------------------------------------
// Kernel 2 (fused): block = (d, 32-wide o-tile); 2048 blocks = 8 blocks/CU
// for read-latency hiding. Each of 4 waves packs 8 w rows straight from
// global (read exactly once, fully coalesced) into LDS; packed x tile comes
// from d_ws. Thread owns o = tid&31 and 8 b's:
// matches = 512 - popcount(x ^ w); out = (matches > bias) as int32.
// ---------------------------------------------------------------------------
__global__ __launch_bounds__(256)
void fused_kernel(const void* __restrict__ w, const u64* __restrict__ px,
                  const float* __restrict__ bias, int* __restrict__ out) {
    __shared__ u64 wp[OT][9];   // +1 pad: strided one-time read <=4-way
    __shared__ u64 xp[BB][8];   // Phase-C reads are wave-broadcast

    const int tid  = threadIdx.x;
    const int blk  = blockIdx.x;
    const int d    = blk >> 4;           // 16 o-tiles per d
    const int o0   = (blk & 15) * OT;
    const int wv   = tid >> 6;
    const int lane = tid & 63;

    const int mode = detect_mode((const u32*)w);

    // Pack 8 w rows per wave: coalesced loads + ballots; unrolled for ILP.
#pragma unroll
    for (int r = 0; r < 8; ++r) {
        const int o = wv * 8 + r;
        u64 my = pack_row(w, ((size_t)(d * OO + o0 + o)) * II, mode, lane);
        if (lane < 8) wp[o][lane] = my;
    }
    // Packed x tile: 512 u64 / 256 threads = 2 each (64B per b-row, L2-hot).
#pragma unroll
    for (int t = tid; t < BB * 8; t += 256) {
        int b = t >> 3, k = t & 7;
        xp[b][k] = px[(size_t)(b * DD + d) * 8 + k];
    }
    const float bv = bias[d * OO + o0 + (tid & 31)];
    __syncthreads();

    const int o  = tid & 31;
    const int b0 = (tid >> 5) * 8;

    u64 wr[8];
#pragma unroll
    for (int k = 0; k < 8; ++k) wr[k] = wp[o][k];

    int* outp = out + (size_t)d * OO + o0 + o;
#pragma unroll 4
    for (int bi = 0; bi < 8; ++bi) {
        const int b = b0 + bi;
        int m = 0;
#pragma unroll
        for (int k = 0; k < 8; ++k) m += __popcll(xp[b][k] ^ wr[k]);
        const float act = (float)(512 - m);   // exact integer in fp32
        outp[(size_t)b * (DD * OO)] = (act > bv) ? 1 : 0;
    }
}

extern "C" void kernel_launch(void* const* d_in, const int* in_sizes, int n_in,
                              void* d_out, int out_size, void* d_ws, size_t ws_size,
                              hipStream_t stream) {
    const void*  x    = d_in[0];                 // (B, D, I) binary
    const void*  w    = d_in[1];                 // (D, O, I) binary
    const float* bias = (const float*)d_in[2];   // (D, O) f32
    int*         out  = (int*)d_out;             // (B, D, O) bool as int32
    u64*         px   = (u64*)d_ws;              // 512 KB packed x

    pack_x_kernel<<<XROWS / 4, 256, 0, stream>>>(x, w, px);
    fused_kernel<<<DD * (OO / OT), 256, 0, stream>>>(w, px, bias, out);
}

// Round 6
// 38.551 us; speedup vs baseline: 1.0310x; 1.0310x over previous
//
#include <hip/hip_runtime.h>
#include <cstdint>

typedef unsigned long long u64;
typedef unsigned int u32;

#define BB 64
#define DD 128
#define OO 512
#define II 512
#define OT 64              // o-tile per block -> 1024 blocks

// ---------------------------------------------------------------------------
// Input-format detection (uniform -> scalar loads, same result every wave).
// mode 0: raw bytes {0,1} | mode 1: int32 {0,1} | mode 2: float32 {0.f,1.f}
// Round-3 timing evidence says the real data is mode 1 (int32), but keep all
// three paths for robustness; the branch is wave-uniform and costs ~nothing.
// ---------------------------------------------------------------------------
__device__ __forceinline__ int detect_mode(const u32* __restrict__ w) {
    bool all01 = true, allf = true;
#pragma unroll
    for (int i = 0; i < 32; ++i) {
        u32 v = w[i];
        all01 = all01 && (v <= 1u);
        allf  = allf  && (v == 0u || v == 0x3F800000u);
    }
    return all01 ? 1 : (allf ? 2 : 0);
}

// ---------------------------------------------------------------------------
// Wave-cooperatively pack one 512-element binary row into 8 u64 words.
// Loads are lane-adjacent and fully coalesced (mode 1/2: two dwordx4 = 1KB
// contiguous fully-used per wave-instr). 8 ballots produce the packed words;
// the bit mapping is a fixed bijection identical for x and w rows, so
// popcount(xor) counts mismatches exactly. Lane j (j<8) returns word j.
// ---------------------------------------------------------------------------
__device__ __forceinline__ u64 pack_row(const void* __restrict__ src,
                                        size_t elem0, int mode, int lane) {
    u64 my = 0;
    if (mode == 0) {
        u64 v = *(const u64*)((const uint8_t*)src + elem0 + (size_t)lane * 8);
#pragma unroll
        for (int j = 0; j < 8; ++j) {
            u64 bj = __ballot(((u32)(v >> (8 * j))) & 1u);
            if (lane == j) my = bj;
        }
    } else {
        const u32 sh = (mode == 1) ? 0u : 23u;   // int32: bit0; float: bit23
        const uint4* p = (const uint4*)((const u32*)src + elem0);
        uint4 v0 = p[lane];        // elems [4L, 4L+4)
        uint4 v1 = p[64 + lane];   // elems [256+4L, 256+4L+4)
        u32 b0 = (v0.x >> sh) & 1u, b1 = (v0.y >> sh) & 1u;
        u32 b2 = (v0.z >> sh) & 1u, b3 = (v0.w >> sh) & 1u;
        u32 b4 = (v1.x >> sh) & 1u, b5 = (v1.y >> sh) & 1u;
        u32 b6 = (v1.z >> sh) & 1u, b7 = (v1.w >> sh) & 1u;
        u64 w0 = __ballot(b0), w1 = __ballot(b1), w2 = __ballot(b2), w3 = __ballot(b3);
        u64 w4 = __ballot(b4), w5 = __ballot(b5), w6 = __ballot(b6), w7 = __ballot(b7);
        if (lane == 0) my = w0;  if (lane == 1) my = w1;
        if (lane == 2) my = w2;  if (lane == 3) my = w3;
        if (lane == 4) my = w4;  if (lane == 5) my = w5;
        if (lane == 6) my = w6;  if (lane == 7) my = w7;
    }
    return my;
}

// ---------------------------------------------------------------------------
// Single fused kernel. Block = (d, 64-wide o-tile); 1024 blocks.
// XCD swizzle co-locates the 8 o-tiles of each d on one XCD so the 7 x-slice
// re-reads hit that XCD's L2 (x slice per d = 128KB << 4MB).
// Each of 4 waves packs 16 w rows (HBM stream, read once) and 16 x rows
// (L2/L3-hot after first tile) via coalesced loads + ballots into LDS.
// Phase C: thread owns o = tid&63 and 16 b's:
//   matches = 512 - popcount(x ^ w); out = (matches > bias) as int32.
// ---------------------------------------------------------------------------
__global__ __launch_bounds__(256)
void binlin_one(const void* __restrict__ x, const void* __restrict__ w,
                const float* __restrict__ bias, int* __restrict__ out) {
    __shared__ u64 wp[OT][9];   // +1 pad: Phase-C strided read <=4-way
    __shared__ u64 xp[BB][8];   // Phase-C reads are wave-broadcast

    const int tid  = threadIdx.x;
    const int bid  = blockIdx.x;
    // swizzle: xcd = bid&7 handles 16 consecutive d's; t = o-tile within d
    const int xcd = bid & 7;
    const int idx = bid >> 3;            // 0..127
    const int d   = xcd * 16 + (idx >> 3);
    const int o0  = (idx & 7) * OT;
    const int wv   = tid >> 6;
    const int lane = tid & 63;

    const int mode = detect_mode((const u32*)w);

    // w tile: 16 rows per wave, issued first (long HBM latency, read once)
#pragma unroll
    for (int r = 0; r < 16; ++r) {
        const int o = wv * 16 + r;
        u64 my = pack_row(w, ((size_t)(d * OO + o0 + o)) * II, mode, lane);
        if (lane < 8) wp[o][lane] = my;
    }
    // x tile: 16 rows per wave (b-major rows, stride 256KB; L2/L3-hot)
#pragma unroll
    for (int r = 0; r < 16; ++r) {
        const int b = wv * 16 + r;
        u64 my = pack_row(x, ((size_t)(b * DD + d)) * II, mode, lane);
        if (lane < 8) xp[b][lane] = my;
    }
    const float bv = bias[d * OO + o0 + (tid & 63)];
    __syncthreads();

    const int o  = tid & 63;
    const int b0 = (tid >> 6) * 16;

    u64 wr[8];
#pragma unroll
    for (int k = 0; k < 8; ++k) wr[k] = wp[o][k];

    int* outp = out + (size_t)d * OO + o0 + o;
#pragma unroll 4
    for (int bi = 0; bi < 16; ++bi) {
        const int b = b0 + bi;
        int m = 0;
#pragma unroll
        for (int k = 0; k < 8; ++k) m += __popcll(xp[b][k] ^ wr[k]);
        const float act = (float)(512 - m);   // exact integer in fp32
        outp[(size_t)b * (DD * OO)] = (act > bv) ? 1 : 0;
    }
}

extern "C" void kernel_launch(void* const* d_in, const int* in_sizes, int n_in,
                              void* d_out, int out_size, void* d_ws, size_t ws_size,
                              hipStream_t stream) {
    const void*  x    = d_in[0];                 // (B, D, I) binary
    const void*  w    = d_in[1];                 // (D, O, I) binary
    const float* bias = (const float*)d_in[2];   // (D, O) f32
    int*         out  = (int*)d_out;             // (B, D, O) bool as int32

    binlin_one<<<DD * (OO / OT), 256, 0, stream>>>(x, w, bias, out);
}

// Round 7
// 35.394 us; speedup vs baseline: 1.1230x; 1.0892x over previous
//
#include <hip/hip_runtime.h>
#include <cstdint>

typedef unsigned long long u64;
typedef unsigned int u32;

#define BB 64
#define DD 128
#define OO 512
#define II 512
#define OT 64              // o-tile per block -> 1024 blocks

// ---------------------------------------------------------------------------
// Input-format detection (uniform -> scalar loads).
// mode 0: raw bytes {0,1} | mode 1: int32 {0,1} | mode 2: float32 {0.f,1.f}
// Round-6 counter evidence (cold FETCH=74MB < int32 compulsory 134MB) says
// the real data is mode 0 (bytes); keep the others for robustness.
// ---------------------------------------------------------------------------
__device__ __forceinline__ int detect_mode(const u32* __restrict__ w) {
    bool all01 = true, allf = true;
#pragma unroll
    for (int i = 0; i < 32; ++i) {
        u32 v = w[i];
        all01 = all01 && (v <= 1u);
        allf  = allf  && (v == 0u || v == 0x3F800000u);
    }
    return all01 ? 1 : (allf ? 2 : 0);
}

// 8 ballots pack one row's 512 bytes (held as u64 per lane: bytes
// [8L, 8L+8)) into 8 u64 words; lane j (j<8) keeps word j. The bit
// bijection (elem 8L+j -> word j bit L) is identical for x and w rows, so
// popcount(xor) counts mismatches exactly.
__device__ __forceinline__ u64 ballots8_bytes(u64 v, int lane) {
    u64 keep = 0;
#pragma unroll
    for (int j = 0; j < 8; ++j) {
        u64 bj = __ballot((u32)(v >> (8 * j)) & 1u);
        if (lane == j) keep = bj;
    }
    return keep;
}

// Same for one row held as two uint4 (mode 1/2: lane has elems [4L,4L+4) and
// [256+4L,256+4L+4)); sh selects the value bit (0 for int, 23 for float 1.0f).
__device__ __forceinline__ u64 ballots8_words(uint4 a, uint4 b, u32 sh, int lane) {
    u64 w0 = __ballot((a.x >> sh) & 1u), w1 = __ballot((a.y >> sh) & 1u);
    u64 w2 = __ballot((a.z >> sh) & 1u), w3 = __ballot((a.w >> sh) & 1u);
    u64 w4 = __ballot((b.x >> sh) & 1u), w5 = __ballot((b.y >> sh) & 1u);
    u64 w6 = __ballot((b.z >> sh) & 1u), w7 = __ballot((b.w >> sh) & 1u);
    u64 keep = 0;
    if (lane == 0) keep = w0;  if (lane == 1) keep = w1;
    if (lane == 2) keep = w2;  if (lane == 3) keep = w3;
    if (lane == 4) keep = w4;  if (lane == 5) keep = w5;
    if (lane == 6) keep = w6;  if (lane == 7) keep = w7;
    return keep;
}

// ---------------------------------------------------------------------------
// Single kernel. Block = (d, 64-wide o-tile); 1024 blocks (4/CU).
// XCD swizzle co-locates the 8 o-tiles of each d on one XCD.
// Pack phase (mode 0): ALL 32 row-loads (16 w + 16 x) issued before any
// ballot -> 16KB in flight per wave, hides HBM latency (round-6 fix:
// VGPR=48 meant ~2 loads in flight; this was the latency wall).
// Phase C: thread owns o = tid&63 and 16 b's:
//   matches = 512 - popcount(x ^ w); out = (matches > bias) as int32.
// ---------------------------------------------------------------------------
__global__ __launch_bounds__(256, 4)
void binlin_one(const void* __restrict__ x, const void* __restrict__ w,
                const float* __restrict__ bias, int* __restrict__ out) {
    __shared__ u64 wp[OT][9];   // +1 pad: Phase-C strided read <=4-way
    __shared__ u64 xp[BB][8];   // Phase-C reads are wave-broadcast

    const int tid  = threadIdx.x;
    const int bid  = blockIdx.x;
    const int xcd  = bid & 7;
    const int idx  = bid >> 3;           // 0..127
    const int d    = xcd * 16 + (idx >> 3);
    const int o0   = (idx & 7) * OT;
    const int wv   = tid >> 6;
    const int lane = tid & 63;

    const int mode = detect_mode((const u32*)w);

    if (mode == 0) {
        const uint8_t* wb = (const uint8_t*)w;
        const uint8_t* xb = (const uint8_t*)x;
        const size_t wbase = ((size_t)(d * OO + o0 + wv * 16)) * II + (size_t)lane * 8;

        u64 vw[16], vx[16];
        // all 32 loads issued back-to-back: max VMEM ILP
#pragma unroll
        for (int r = 0; r < 16; ++r)
            vw[r] = *(const u64*)(wb + wbase + (size_t)r * II);
#pragma unroll
        for (int r = 0; r < 16; ++r)
            vx[r] = *(const u64*)(xb + ((size_t)(wv * 16 + r) * DD + d) * II
                                     + (size_t)lane * 8);
        // dense ballot phase
#pragma unroll
        for (int r = 0; r < 16; ++r) {
            u64 kw = ballots8_bytes(vw[r], lane);
            if (lane < 8) wp[wv * 16 + r][lane] = kw;
        }
#pragma unroll
        for (int r = 0; r < 16; ++r) {
            u64 kx = ballots8_bytes(vx[r], lane);
            if (lane < 8) xp[wv * 16 + r][lane] = kx;
        }
    } else {
        const u32 sh = (mode == 1) ? 0u : 23u;
        const u32* ww = (const u32*)w;
        const u32* xw = (const u32*)x;
        // 4-row batches (8 dwordx4 in flight) to stay in VGPR budget
#pragma unroll
        for (int batch = 0; batch < 4; ++batch) {
            uint4 a[4], b4[4];
            const size_t ebase = (size_t)(d * OO + o0 + wv * 16 + batch * 4) * II;
#pragma unroll
            for (int r = 0; r < 4; ++r) {
                const uint4* p = (const uint4*)(ww + ebase + (size_t)r * II);
                a[r] = p[lane]; b4[r] = p[64 + lane];
            }
#pragma unroll
            for (int r = 0; r < 4; ++r) {
                u64 k = ballots8_words(a[r], b4[r], sh, lane);
                if (lane < 8) wp[wv * 16 + batch * 4 + r][lane] = k;
            }
        }
#pragma unroll
        for (int batch = 0; batch < 4; ++batch) {
            uint4 a[4], b4[4];
#pragma unroll
            for (int r = 0; r < 4; ++r) {
                const int b = wv * 16 + batch * 4 + r;
                const uint4* p = (const uint4*)(xw + ((size_t)b * DD + d) * II);
                a[r] = p[lane]; b4[r] = p[64 + lane];
            }
#pragma unroll
            for (int r = 0; r < 4; ++r) {
                u64 k = ballots8_words(a[r], b4[r], sh, lane);
                if (lane < 8) xp[wv * 16 + batch * 4 + r][lane] = k;
            }
        }
    }
    const float bv = bias[d * OO + o0 + (tid & 63)];
    __syncthreads();

    const int o  = tid & 63;
    const int b0 = (tid >> 6) * 16;

    u64 wr[8];
#pragma unroll
    for (int k = 0; k < 8; ++k) wr[k] = wp[o][k];

    int* outp = out + (size_t)d * OO + o0 + o;
#pragma unroll 4
    for (int bi = 0; bi < 16; ++bi) {
        const int b = b0 + bi;
        int m = 0;
#pragma unroll
        for (int k = 0; k < 8; ++k) m += __popcll(xp[b][k] ^ wr[k]);
        const float act = (float)(512 - m);   // exact integer in fp32
        outp[(size_t)b * (DD * OO)] = (act > bv) ? 1 : 0;
    }
}

extern "C" void kernel_launch(void* const* d_in, const int* in_sizes, int n_in,
                              void* d_out, int out_size, void* d_ws, size_t ws_size,
                              hipStream_t stream) {
    const void*  x    = d_in[0];                 // (B, D, I) binary bytes
    const void*  w    = d_in[1];                 // (D, O, I) binary bytes
    const float* bias = (const float*)d_in[2];   // (D, O) f32
    int*         out  = (int*)d_out;             // (B, D, O) bool as int32

    binlin_one<<<DD * (OO / OT), 256, 0, stream>>>(x, w, bias, out);
}